// Round 15
// baseline (549.222 us; speedup 1.0000x reference)
//
#include <hip/hip_runtime.h>
#include <math.h>

#define C 64
#define NL 30
#define T 16384
#define B 4

typedef __bf16 bf16_t;
typedef __bf16 bf16x8 __attribute__((ext_vector_type(8)));
typedef __bf16 bf16x4 __attribute__((ext_vector_type(4)));
typedef float f32x4 __attribute__((ext_vector_type(4)));

typedef const __attribute__((address_space(1))) unsigned int glb_u32;
typedef __attribute__((address_space(3))) unsigned int lds_u32;

constexpr float INV_SQRT2   = 0.70710678118654752440f;
constexpr float INV_SQRT_NL = 0.18257418583505537115f; // 1/sqrt(30)

__device__ __forceinline__ float fsig(float x) {
    return __builtin_amdgcn_rcpf(1.f + __builtin_amdgcn_exp2f(-1.44269504089f * x));
}
__device__ __forceinline__ float ftanh(float x) {
    return fmaf(2.f, __builtin_amdgcn_rcpf(1.f + __builtin_amdgcn_exp2f(-2.88539008178f * x)), -1.f);
}
// XOR swizzle for 128-byte-row LDS tiles (G4): byte ^= ((row&7)<<4)
__device__ __forceinline__ int swz(int off) { return off ^ ((off >> 3) & 0x70); }

// ---------------------------------------------------------------------------
// Pack weights to bf16 K-contiguous rows.
// ---------------------------------------------------------------------------
__global__ void pack_weights(const float* __restrict__ dw_W,
                             const float* __restrict__ op_W,
                             const float* __restrict__ sk_W,
                             bf16_t* __restrict__ convpk,
                             bf16_t* __restrict__ oppk,
                             bf16_t* __restrict__ skpk) {
    int idx = blockIdx.x * 256 + threadIdx.x;
    const int ndw = NL * 128 * 192;
    const int nop = NL * 128 * 64;
    if (idx < ndw) {
        int k = idx % 192; int r = idx / 192;
        int oc = r % 128;  int l = r / 128;
        int tap = k >> 6, ic = k & 63;
        convpk[idx] = (bf16_t)dw_W[((l * 128 + oc) * 64 + ic) * 3 + tap];
    } else if (idx < ndw + nop) {
        oppk[idx - ndw] = (bf16_t)op_W[idx - ndw];
    } else if (idx < ndw + nop + 4096) {
        int j = idx - ndw - nop;
        skpk[j] = (bf16_t)(sk_W[j] * INV_SQRT_NL);
    }
}

// ---------------------------------------------------------------------------
__global__ void cond_embp1(const int* __restrict__ step,
                           const float* __restrict__ p1_W, const float* __restrict__ p1_b,
                           float* __restrict__ h1out) {
    __shared__ float e[128];
    __shared__ float red[256];
    int b = blockIdx.x, blk = blockIdx.y, tid = threadIdx.x;
    int s = step[b];
    if (tid < 128) {
        int d = tid & 63;
        float tf = (float)s * powf(10.f, (float)d * 4.f / 63.f);
        double td = (double)tf;
        e[tid] = (tid < 64) ? (float)sin(td) : (float)cos(td);
    }
    __syncthreads();
    int ol = tid >> 2, q = tid & 3;
    int o = blk * 64 + ol;
    const float4* wr = (const float4*)(p1_W + o * 128 + q * 32);
    const float4* ev = (const float4*)(e + q * 32);
    float a = 0.f;
    #pragma unroll
    for (int j = 0; j < 8; ++j) {
        float4 wv = wr[j]; float4 xv = ev[j];
        a = fmaf(wv.x, xv.x, a); a = fmaf(wv.y, xv.y, a);
        a = fmaf(wv.z, xv.z, a); a = fmaf(wv.w, xv.w, a);
    }
    red[tid] = a;
    __syncthreads();
    if (q == 0) {
        float v = red[tid] + red[tid + 1] + red[tid + 2] + red[tid + 3] + p1_b[o];
        h1out[b * 512 + o] = v / (1.f + expf(-v));
    }
}

// ---------------------------------------------------------------------------
__global__ void cond_p2(const float* __restrict__ h1,
                        const float* __restrict__ p2_W, const float* __restrict__ p2_b,
                        float* __restrict__ h2out) {
    __shared__ float red[256];
    int b = blockIdx.x, blk = blockIdx.y, tid = threadIdx.x;
    int ol = tid >> 2, q = tid & 3;
    int o = blk * 64 + ol;
    const float4* wr = (const float4*)(p2_W + o * 512 + q * 128);
    const float4* hv = (const float4*)(h1 + b * 512 + q * 128);
    float a = 0.f;
    #pragma unroll 8
    for (int j = 0; j < 32; ++j) {
        float4 wv = wr[j]; float4 xv = hv[j];
        a = fmaf(wv.x, xv.x, a); a = fmaf(wv.y, xv.y, a);
        a = fmaf(wv.z, xv.z, a); a = fmaf(wv.w, xv.w, a);
    }
    red[tid] = a;
    __syncthreads();
    if (q == 0) {
        float v = red[tid] + red[tid + 1] + red[tid + 2] + red[tid + 3] + p2_b[o];
        h2out[b * 512 + o] = v / (1.f + expf(-v));
    }
}

// ---------------------------------------------------------------------------
__global__ void cond_stage2b(const float* __restrict__ h2,
                             const float* __restrict__ dp_W, const float* __restrict__ dp_b,
                             const bf16_t* __restrict__ convpk,
                             const float* __restrict__ dw_b,
                             float* __restrict__ bias2) {
    __shared__ float red[256];
    __shared__ float cond_s[64];
    int l = blockIdx.x, b = blockIdx.y;
    int tid = threadIdx.x;
    {
        int o = tid >> 2, q = tid & 3;
        const float4* wr = (const float4*)(dp_W + ((size_t)l * C + o) * 512 + q * 128);
        const float4* h = (const float4*)(h2 + b * 512 + q * 128);
        float a = 0.f;
        #pragma unroll 8
        for (int j = 0; j < 32; ++j) {
            float4 wv = wr[j]; float4 hv = h[j];
            a = fmaf(wv.x, hv.x, a); a = fmaf(wv.y, hv.y, a);
            a = fmaf(wv.z, hv.z, a); a = fmaf(wv.w, hv.w, a);
        }
        red[tid] = a;
        __syncthreads();
        if (q == 0)
            cond_s[o] = red[tid] + red[tid + 1] + red[tid + 2] + red[tid + 3] + dp_b[l * C + o];
    }
    __syncthreads();
    int oc = tid & 127, kh = tid >> 7;
    const bf16_t* wr = convpk + ((size_t)l * 128 + oc) * 192 + kh * 96;
    float a = kh ? 0.f : dw_b[l * 128 + oc];
    #pragma unroll
    for (int j = 0; j < 96; ++j)
        a = fmaf((float)wr[j], cond_s[(kh * 96 + j) & 63], a);
    __syncthreads();
    red[tid] = a;
    __syncthreads();
    if (tid < 128)
        bias2[(l * B + b) * 128 + tid] = red[tid] + red[tid + 128];
}

// ---------------------------------------------------------------------------
// Single layer, 64-t tile. Grid (256, B) = 1024 blocks -> 3 blocks/CU at
// natural VGPR (~150): NO __launch_bounds__ min-waves (R12's (256,4) cap
// caused spills). FROMAUD=1 (layer 0, dil==1): x slab computed in-LDS from
// audio (writes to swz() dest = true value at swizzled address, matching
// the swizzled reads). Same XCD mapping as all other kernels: tile j ->
// XCD (j>>5)&7 -> per-XCD contiguous layer-invariant 2048-t range.
// LDS 32KB: 3 slices [64t][64c] bf16 (24KB) + z (8KB).
// ---------------------------------------------------------------------------
template<int FROMAUD>
__global__ __launch_bounds__(256) void layer_kernel(
    const bf16_t* __restrict__ x_in, bf16_t* __restrict__ x_out, bf16_t* __restrict__ skip,
    const bf16_t* __restrict__ convpk, const bf16_t* __restrict__ oppk,
    const float* __restrict__ bias2, const float* __restrict__ op_b,
    const bf16_t* __restrict__ zpage,
    const float* __restrict__ audio,
    const float* __restrict__ in_W, const float* __restrict__ in_b,
    int layer, int dil, int first)
{
    __shared__ uint4 smem_u[2048];                       // 32768 B
    char* sm = (char*)smem_u;

    int tid = threadIdx.x;
    int w = __builtin_amdgcn_readfirstlane(tid >> 6);
    int l = tid & 63;
    int lr = l & 15;
    int g = l >> 4;
    int b = blockIdx.y;
    int bid = blockIdx.x;                                // 256 tiles
    int tile = ((bid & 7) << 5) + (bid >> 3);            // XCD swizzle (bijective)
    int t0 = tile * 64;
    const bf16_t* xb = x_in + (size_t)b * T * 64;
    size_t bb = (size_t)b * T * 64;

    // ---- stage 3 shifted slices ------------------------------------------
    if constexpr (FROMAUD) {
        // dil == 1: compute x = relu(in_W*audio + in_b) directly into slab
        #pragma unroll
        for (int it = 0; it < 6; ++it) {
            int q = it * 256 + tid;
            int slice = q >> 9, row = (q >> 3) & 63, c16 = q & 7;
            int ts = t0 + row + (slice - 1);
            bf16x8 o;
            if ((unsigned)ts < (unsigned)T) {
                float av = audio[(size_t)b * T + ts];
                #pragma unroll
                for (int j = 0; j < 8; ++j) {
                    int c = c16 * 8 + j;
                    o[j] = (bf16_t)fmaxf(fmaf(in_W[c], av, in_b[c]), 0.f);
                }
            } else {
                #pragma unroll
                for (int j = 0; j < 8; ++j) o[j] = (bf16_t)0.f;
            }
            *(bf16x8*)(sm + swz(slice * 8192 + row * 128 + c16 * 16)) = o;
        }
    } else {
        #pragma unroll
        for (int it = 0; it < 6; ++it) {
            int qq = it * 256 + tid;
            int slice = qq >> 9, row = (qq >> 3) & 63, c16 = qq & 7;
            int ts = t0 + row + (slice - 1) * dil;
            int c16s = c16 ^ (row & 7);                  // swizzle on SOURCE
            const bf16_t* src = ((unsigned)ts < (unsigned)T)
                ? (xb + (size_t)ts * 64 + c16s * 8)
                : (zpage + c16s * 8);
            __builtin_amdgcn_global_load_lds((glb_u32*)src,
                (lds_u32*)(sm + it * 4096 + w * 1024), 16, 0, 0);
        }
    }

    // ---- weights + biases (overlap stage latency) ------------------------
    bf16x8 cA[2][6];
    const bf16_t* cw = convpk + (size_t)layer * 128 * 192;
    #pragma unroll
    for (int mf = 0; mf < 2; ++mf)
        #pragma unroll
        for (int kf = 0; kf < 6; ++kf)
            cA[mf][kf] = *(const bf16x8*)(cw + (mf * 64 + w * 16 + lr) * 192 + kf * 32 + g * 8);
    bf16x8 oA[2][2];
    const bf16_t* ow = oppk + (size_t)layer * 128 * 64;
    #pragma unroll
    for (int mf = 0; mf < 2; ++mf)
        #pragma unroll
        for (int kf = 0; kf < 2; ++kf)
            oA[mf][kf] = *(const bf16x8*)(ow + (mf * 64 + w * 16 + lr) * 64 + kf * 32 + g * 8);
    f32x4 bC[2], bO[2];
    const float* b2 = bias2 + (layer * B + b) * 128;
    const float* ob = op_b + layer * 2 * C;
    #pragma unroll
    for (int mf = 0; mf < 2; ++mf)
        #pragma unroll
        for (int r = 0; r < 4; ++r) {
            bC[mf][r] = b2[mf * 64 + w * 16 + g * 4 + r];
            bO[mf][r] = ob[mf * 64 + w * 16 + g * 4 + r];
        }
    __syncthreads();                                    // stage done

    // ---- conv GEMM: K = 3 taps x 64 c ------------------------------------
    f32x4 acc[2][4];
    #pragma unroll
    for (int mf = 0; mf < 2; ++mf)
        #pragma unroll
        for (int nf = 0; nf < 4; ++nf) acc[mf][nf] = bC[mf];
    #pragma unroll
    for (int kf = 0; kf < 6; ++kf) {
        int tap = kf >> 1;
        int kc = (kf & 1) * 32;
        bf16x8 Bf[4];
        #pragma unroll
        for (int nf = 0; nf < 4; ++nf) {
            int off = tap * 8192 + (nf * 16 + lr) * 128 + (kc + g * 8) * 2;
            Bf[nf] = *(const bf16x8*)(sm + swz(off));
        }
        #pragma unroll
        for (int mf = 0; mf < 2; ++mf)
            #pragma unroll
            for (int nf = 0; nf < 4; ++nf)
                acc[mf][nf] = __builtin_amdgcn_mfma_f32_16x16x32_bf16(
                    cA[mf][kf], Bf[nf], acc[mf][nf], 0, 0, 0);
    }

    // ---- gating in-lane, z -> LDS in B-frag layout -----------------------
    #pragma unroll
    for (int nf = 0; nf < 4; ++nf) {
        union { bf16_t hh[4]; uint2 u; } zp;
        #pragma unroll
        for (int r = 0; r < 4; ++r)
            zp.hh[r] = (bf16_t)(fsig(acc[0][nf][r]) * ftanh(acc[1][nf][r]));
        int off = 24576 + (nf * 16 + lr) * 128 + (w * 16 + g * 4) * 2;
        *(uint2*)(sm + swz(off)) = zp.u;
    }
    __syncthreads();                                    // z ready

    // ---- op 1x1 GEMM ------------------------------------------------------
    f32x4 acc2[2][4];
    #pragma unroll
    for (int mf = 0; mf < 2; ++mf)
        #pragma unroll
        for (int nf = 0; nf < 4; ++nf) acc2[mf][nf] = bO[mf];
    #pragma unroll
    for (int kf = 0; kf < 2; ++kf) {
        bf16x8 Zf[4];
        #pragma unroll
        for (int nf = 0; nf < 4; ++nf) {
            int off = 24576 + (nf * 16 + lr) * 128 + (kf * 32 + g * 8) * 2;
            Zf[nf] = *(const bf16x8*)(sm + swz(off));
        }
        #pragma unroll
        for (int mf = 0; mf < 2; ++mf)
            #pragma unroll
            for (int nf = 0; nf < 4; ++nf)
                acc2[mf][nf] = __builtin_amdgcn_mfma_f32_16x16x32_bf16(
                    oA[mf][kf], Zf[nf], acc2[mf][nf], 0, 0, 0);
    }

    // ---- epilogue: residual + skip ---------------------------------------
    #pragma unroll
    for (int nf = 0; nf < 4; ++nf) {
        int t = t0 + nf * 16 + lr;
        int c0 = w * 16 + g * 4;
        int xoff = 8192 + (nf * 16 + lr) * 128 + c0 * 2;   // tap-1 slice
        bf16x4 xv = *(const bf16x4*)(sm + swz(xoff));
        bf16x4 ro, so;
        bf16_t* sp = skip + bb + (size_t)t * 64 + c0;
        if (first) {
            #pragma unroll
            for (int r = 0; r < 4; ++r) {
                ro[r] = (bf16_t)(((float)xv[r] + acc2[0][nf][r]) * INV_SQRT2);
                so[r] = (bf16_t)acc2[1][nf][r];
            }
        } else {
            bf16x4 sv = *(const bf16x4*)sp;
            #pragma unroll
            for (int r = 0; r < 4; ++r) {
                ro[r] = (bf16_t)(((float)xv[r] + acc2[0][nf][r]) * INV_SQRT2);
                so[r] = (bf16_t)((float)sv[r] + acc2[1][nf][r]);
            }
        }
        *(bf16x4*)(x_out + bb + (size_t)t * 64 + c0) = ro;
        *(bf16x4*)sp = so;
    }
}

// ---------------------------------------------------------------------------
// Final: skip -> sk conv (MFMA, pre-scaled) -> relu -> dot out_W + out_b.
// ---------------------------------------------------------------------------
__global__ __launch_bounds__(256) void final_kernel(
    const bf16_t* __restrict__ skip, const bf16_t* __restrict__ skpk,
    const float* __restrict__ sk_b,
    const float* __restrict__ out_W, const float* __restrict__ out_b,
    float* __restrict__ out)
{
    __shared__ uint4 tile_u[512];
    __shared__ float part[16][66];
    unsigned char* sm = (unsigned char*)tile_u;
    int tid = threadIdx.x;
    int w = __builtin_amdgcn_readfirstlane(tid >> 6);
    int l = tid & 63, lr = l & 15, g = l >> 4;
    int bid = blockIdx.x;
    int tile = ((bid & 7) << 5) + (bid >> 3);
    int b = blockIdx.y, t0 = tile * 64;
    const bf16_t* sb = skip + (size_t)b * T * 64;

    #pragma unroll
    for (int it = 0; it < 2; ++it) {
        int q = it * 256 + tid;
        int row = q >> 3, c16 = q & 7;
        uint4 val = *(const uint4*)(sb + (size_t)(t0 + row) * 64 + c16 * 8);
        *(uint4*)(sm + swz(row * 128 + c16 * 16)) = val;
    }

    bf16x8 aS[2];
    #pragma unroll
    for (int kf = 0; kf < 2; ++kf)
        aS[kf] = *(const bf16x8*)(skpk + (w * 16 + lr) * 64 + kf * 32 + g * 8);
    f32x4 acc[4];
    #pragma unroll
    for (int nf = 0; nf < 4; ++nf)
        #pragma unroll
        for (int r = 0; r < 4; ++r) acc[nf][r] = sk_b[w * 16 + g * 4 + r];
    __syncthreads();

    #pragma unroll
    for (int kf = 0; kf < 2; ++kf) {
        bf16x8 Bf[4];
        #pragma unroll
        for (int nf = 0; nf < 4; ++nf) {
            int off = (nf * 16 + lr) * 128 + (kf * 32 + g * 8) * 2;
            Bf[nf] = *(const bf16x8*)(sm + swz(off));
        }
        #pragma unroll
        for (int nf = 0; nf < 4; ++nf)
            acc[nf] = __builtin_amdgcn_mfma_f32_16x16x32_bf16(aS[kf], Bf[nf], acc[nf], 0, 0, 0);
    }

    #pragma unroll
    for (int nf = 0; nf < 4; ++nf) {
        float o = 0.f;
        #pragma unroll
        for (int r = 0; r < 4; ++r)
            o = fmaf(out_W[w * 16 + g * 4 + r], fmaxf(acc[nf][r], 0.f), o);
        part[w * 4 + g][nf * 16 + lr] = o;
    }
    __syncthreads();
    if (tid < 64) {
        float o = out_b[0];
        #pragma unroll
        for (int j = 0; j < 16; ++j) o += part[j][tid];
        out[(size_t)b * T + t0 + tid] = o;
    }
}

// ---------------------------------------------------------------------------
extern "C" void kernel_launch(void* const* d_in, const int* in_sizes, int n_in,
                              void* d_out, int out_size, void* d_ws, size_t ws_size,
                              hipStream_t stream) {
    const float* audio = (const float*)d_in[0];
    const int*   dstep = (const int*)d_in[1];
    const float* in_W  = (const float*)d_in[2];
    const float* in_b  = (const float*)d_in[3];
    const float* p1_W  = (const float*)d_in[4];
    const float* p1_b  = (const float*)d_in[5];
    const float* p2_W  = (const float*)d_in[6];
    const float* p2_b  = (const float*)d_in[7];
    const float* dw_W  = (const float*)d_in[8];
    const float* dw_b  = (const float*)d_in[9];
    const float* dp_W  = (const float*)d_in[10];
    const float* dp_b  = (const float*)d_in[11];
    const float* op_W  = (const float*)d_in[12];
    const float* op_b  = (const float*)d_in[13];
    const float* sk_W  = (const float*)d_in[14];
    const float* sk_b  = (const float*)d_in[15];
    const float* out_W = (const float*)d_in[16];
    const float* out_b = (const float*)d_in[17];

    float* ws = (float*)d_ws;
    const size_t NXE = (size_t)B * T * 64;
    float* h1    = ws;
    float* h2    = h1 + B * 512;
    float* bias2 = h2 + B * 512;                        // NL*B*128
    float* zpg   = bias2 + NL * B * 128;                // 512B zero page
    bf16_t* xA   = (bf16_t*)(zpg + 128);
    bf16_t* xB   = xA + NXE;
    bf16_t* skip = xB + NXE;
    bf16_t* convpk = skip + NXE;
    bf16_t* oppk   = convpk + (size_t)NL * 128 * 192;
    bf16_t* skpk   = oppk + (size_t)NL * 128 * 64;

    hipMemsetAsync(zpg, 0, 512, stream);
    hipLaunchKernelGGL(pack_weights, dim3(3856), dim3(256), 0, stream,
                       dw_W, op_W, sk_W, convpk, oppk, skpk);
    hipLaunchKernelGGL(cond_embp1, dim3(B, 8), dim3(256), 0, stream,
                       dstep, p1_W, p1_b, h1);
    hipLaunchKernelGGL(cond_p2, dim3(B, 8), dim3(256), 0, stream,
                       h1, p2_W, p2_b, h2);
    hipLaunchKernelGGL(cond_stage2b, dim3(NL, B), dim3(256), 0, stream,
                       h2, dp_W, dp_b, convpk, dw_b, bias2);

    bf16_t* bufs[2] = { xA, xB };
    int cur = 0;
    const bf16_t* zpgc = (const bf16_t*)zpg;
    for (int i = 0; i < NL; ++i) {
        int dil = 1 << (i % 10);
        if (i == 0) {
            // layer 0: in_conv fused (reads audio directly), writes xB
            hipLaunchKernelGGL((layer_kernel<1>), dim3(256, B), dim3(256), 0, stream,
                               bufs[cur], bufs[cur ^ 1], skip, convpk, oppk,
                               bias2, op_b, zpgc, audio, in_W, in_b, 0, 1, 1);
        } else {
            hipLaunchKernelGGL((layer_kernel<0>), dim3(256, B), dim3(256), 0, stream,
                               bufs[cur], bufs[cur ^ 1], skip, convpk, oppk,
                               bias2, op_b, zpgc, audio, in_W, in_b, i, dil, 0);
        }
        cur ^= 1;
    }
    hipLaunchKernelGGL(final_kernel, dim3(256, B), dim3(256), 0, stream,
                       skip, skpk, sk_b, out_W, out_b, (float*)d_out);
}

// Round 16
// 466.124 us; speedup vs baseline: 1.1783x; 1.1783x over previous
//
#include <hip/hip_runtime.h>
#include <math.h>

#define C 64
#define NL 30
#define T 16384
#define B 4

typedef __bf16 bf16_t;
typedef __bf16 bf16x8 __attribute__((ext_vector_type(8)));
typedef __bf16 bf16x4 __attribute__((ext_vector_type(4)));
typedef float f32x4 __attribute__((ext_vector_type(4)));

typedef const __attribute__((address_space(1))) unsigned int glb_u32;
typedef __attribute__((address_space(3))) unsigned int lds_u32;

constexpr float INV_SQRT2   = 0.70710678118654752440f;
constexpr float INV_SQRT_NL = 0.18257418583505537115f; // 1/sqrt(30)

__device__ __forceinline__ float fsig(float x) {
    return __builtin_amdgcn_rcpf(1.f + __builtin_amdgcn_exp2f(-1.44269504089f * x));
}
__device__ __forceinline__ float ftanh(float x) {
    return fmaf(2.f, __builtin_amdgcn_rcpf(1.f + __builtin_amdgcn_exp2f(-2.88539008178f * x)), -1.f);
}
// XOR swizzle for 128-byte-row LDS tiles (G4): byte ^= ((row&7)<<4)
__device__ __forceinline__ int swz(int off) { return off ^ ((off >> 3) & 0x70); }

// ---------------------------------------------------------------------------
// Pack weights to bf16 K-contiguous rows.
// ---------------------------------------------------------------------------
__global__ void pack_weights(const float* __restrict__ dw_W,
                             const float* __restrict__ op_W,
                             const float* __restrict__ sk_W,
                             bf16_t* __restrict__ convpk,
                             bf16_t* __restrict__ oppk,
                             bf16_t* __restrict__ skpk) {
    int idx = blockIdx.x * 256 + threadIdx.x;
    const int ndw = NL * 128 * 192;
    const int nop = NL * 128 * 64;
    if (idx < ndw) {
        int k = idx % 192; int r = idx / 192;
        int oc = r % 128;  int l = r / 128;
        int tap = k >> 6, ic = k & 63;
        convpk[idx] = (bf16_t)dw_W[((l * 128 + oc) * 64 + ic) * 3 + tap];
    } else if (idx < ndw + nop) {
        oppk[idx - ndw] = (bf16_t)op_W[idx - ndw];
    } else if (idx < ndw + nop + 4096) {
        int j = idx - ndw - nop;
        skpk[j] = (bf16_t)(sk_W[j] * INV_SQRT_NL);
    }
}

// ---------------------------------------------------------------------------
__global__ void cond_embp1(const int* __restrict__ step,
                           const float* __restrict__ p1_W, const float* __restrict__ p1_b,
                           float* __restrict__ h1out) {
    __shared__ float e[128];
    __shared__ float red[256];
    int b = blockIdx.x, blk = blockIdx.y, tid = threadIdx.x;
    int s = step[b];
    if (tid < 128) {
        int d = tid & 63;
        float tf = (float)s * powf(10.f, (float)d * 4.f / 63.f);
        double td = (double)tf;
        e[tid] = (tid < 64) ? (float)sin(td) : (float)cos(td);
    }
    __syncthreads();
    int ol = tid >> 2, q = tid & 3;
    int o = blk * 64 + ol;
    const float4* wr = (const float4*)(p1_W + o * 128 + q * 32);
    const float4* ev = (const float4*)(e + q * 32);
    float a = 0.f;
    #pragma unroll
    for (int j = 0; j < 8; ++j) {
        float4 wv = wr[j]; float4 xv = ev[j];
        a = fmaf(wv.x, xv.x, a); a = fmaf(wv.y, xv.y, a);
        a = fmaf(wv.z, xv.z, a); a = fmaf(wv.w, xv.w, a);
    }
    red[tid] = a;
    __syncthreads();
    if (q == 0) {
        float v = red[tid] + red[tid + 1] + red[tid + 2] + red[tid + 3] + p1_b[o];
        h1out[b * 512 + o] = v / (1.f + expf(-v));
    }
}

// ---------------------------------------------------------------------------
__global__ void cond_p2(const float* __restrict__ h1,
                        const float* __restrict__ p2_W, const float* __restrict__ p2_b,
                        float* __restrict__ h2out) {
    __shared__ float red[256];
    int b = blockIdx.x, blk = blockIdx.y, tid = threadIdx.x;
    int ol = tid >> 2, q = tid & 3;
    int o = blk * 64 + ol;
    const float4* wr = (const float4*)(p2_W + o * 512 + q * 128);
    const float4* hv = (const float4*)(h1 + b * 512 + q * 128);
    float a = 0.f;
    #pragma unroll 8
    for (int j = 0; j < 32; ++j) {
        float4 wv = wr[j]; float4 xv = hv[j];
        a = fmaf(wv.x, xv.x, a); a = fmaf(wv.y, xv.y, a);
        a = fmaf(wv.z, xv.z, a); a = fmaf(wv.w, xv.w, a);
    }
    red[tid] = a;
    __syncthreads();
    if (q == 0) {
        float v = red[tid] + red[tid + 1] + red[tid + 2] + red[tid + 3] + p2_b[o];
        h2out[b * 512 + o] = v / (1.f + expf(-v));
    }
}

// ---------------------------------------------------------------------------
__global__ void cond_stage2b(const float* __restrict__ h2,
                             const float* __restrict__ dp_W, const float* __restrict__ dp_b,
                             const bf16_t* __restrict__ convpk,
                             const float* __restrict__ dw_b,
                             float* __restrict__ bias2) {
    __shared__ float red[256];
    __shared__ float cond_s[64];
    int l = blockIdx.x, b = blockIdx.y;
    int tid = threadIdx.x;
    {
        int o = tid >> 2, q = tid & 3;
        const float4* wr = (const float4*)(dp_W + ((size_t)l * C + o) * 512 + q * 128);
        const float4* h = (const float4*)(h2 + b * 512 + q * 128);
        float a = 0.f;
        #pragma unroll 8
        for (int j = 0; j < 32; ++j) {
            float4 wv = wr[j]; float4 hv = h[j];
            a = fmaf(wv.x, hv.x, a); a = fmaf(wv.y, hv.y, a);
            a = fmaf(wv.z, hv.z, a); a = fmaf(wv.w, hv.w, a);
        }
        red[tid] = a;
        __syncthreads();
        if (q == 0)
            cond_s[o] = red[tid] + red[tid + 1] + red[tid + 2] + red[tid + 3] + dp_b[l * C + o];
    }
    __syncthreads();
    int oc = tid & 127, kh = tid >> 7;
    const bf16_t* wr = convpk + ((size_t)l * 128 + oc) * 192 + kh * 96;
    float a = kh ? 0.f : dw_b[l * 128 + oc];
    #pragma unroll
    for (int j = 0; j < 96; ++j)
        a = fmaf((float)wr[j], cond_s[(kh * 96 + j) & 63], a);
    __syncthreads();
    red[tid] = a;
    __syncthreads();
    if (tid < 128)
        bias2[(l * B + b) * 128 + tid] = red[tid] + red[tid + 128];
}

// ---------------------------------------------------------------------------
// Single layer (large dilations 64..512) — R11-proven 128-t version:
// 256 thr = 4 waves; 2 sequential 64-t sub-tiles amortize weight loads.
// XCD swizzle: layer-invariant contiguous 2048-t range per XCD.
// ---------------------------------------------------------------------------
__global__ __launch_bounds__(256) void layer_kernel(
    const bf16_t* __restrict__ x_in, bf16_t* __restrict__ x_out, bf16_t* __restrict__ skip,
    const bf16_t* __restrict__ convpk, const bf16_t* __restrict__ oppk,
    const float* __restrict__ bias2, const float* __restrict__ op_b,
    const bf16_t* __restrict__ zpage,
    int layer, int dil, int first)
{
    __shared__ uint4 smem_u[2048];                       // 32768 B
    char* sm = (char*)smem_u;

    int tid = threadIdx.x;
    int w = __builtin_amdgcn_readfirstlane(tid >> 6);
    int l = tid & 63;
    int lr = l & 15;
    int g = l >> 4;
    int b = blockIdx.y;
    int bid = blockIdx.x;                                // 128 tiles
    int tile = ((bid & 7) << 4) + (bid >> 3);            // XCD swizzle (bijective)
    int tbase = tile * 128;
    const bf16_t* xb = x_in + (size_t)b * T * 64;

    bf16x8 cA[2][6];
    const bf16_t* cw = convpk + (size_t)layer * 128 * 192;
    #pragma unroll
    for (int mf = 0; mf < 2; ++mf)
        #pragma unroll
        for (int kf = 0; kf < 6; ++kf)
            cA[mf][kf] = *(const bf16x8*)(cw + (mf * 64 + w * 16 + lr) * 192 + kf * 32 + g * 8);
    bf16x8 oA[2][2];
    const bf16_t* ow = oppk + (size_t)layer * 128 * 64;
    #pragma unroll
    for (int mf = 0; mf < 2; ++mf)
        #pragma unroll
        for (int kf = 0; kf < 2; ++kf)
            oA[mf][kf] = *(const bf16x8*)(ow + (mf * 64 + w * 16 + lr) * 64 + kf * 32 + g * 8);
    f32x4 bC[2], bO[2];
    const float* b2 = bias2 + (layer * B + b) * 128;
    const float* ob = op_b + layer * 2 * C;
    #pragma unroll
    for (int mf = 0; mf < 2; ++mf)
        #pragma unroll
        for (int r = 0; r < 4; ++r) {
            bC[mf][r] = b2[mf * 64 + w * 16 + g * 4 + r];
            bO[mf][r] = ob[mf * 64 + w * 16 + g * 4 + r];
        }

    size_t bb = (size_t)b * T * 64;

    for (int st = 0; st < 2; ++st) {
        int t0 = tbase + st * 64;

        #pragma unroll
        for (int it = 0; it < 6; ++it) {
            int qq = it * 256 + tid;
            int slice = qq >> 9, row = (qq >> 3) & 63, c16 = qq & 7;
            int ts = t0 + row + (slice - 1) * dil;
            int c16s = c16 ^ (row & 7);
            const bf16_t* src = ((unsigned)ts < (unsigned)T)
                ? (xb + (size_t)ts * 64 + c16s * 8)
                : (zpage + c16s * 8);
            __builtin_amdgcn_global_load_lds((glb_u32*)src,
                (lds_u32*)(sm + it * 4096 + w * 1024), 16, 0, 0);
        }
        __syncthreads();

        f32x4 acc[2][4];
        #pragma unroll
        for (int mf = 0; mf < 2; ++mf)
            #pragma unroll
            for (int nf = 0; nf < 4; ++nf) acc[mf][nf] = bC[mf];
        #pragma unroll
        for (int kf = 0; kf < 6; ++kf) {
            int tap = kf >> 1;
            int kc = (kf & 1) * 32;
            bf16x8 Bf[4];
            #pragma unroll
            for (int nf = 0; nf < 4; ++nf) {
                int off = tap * 8192 + (nf * 16 + lr) * 128 + (kc + g * 8) * 2;
                Bf[nf] = *(const bf16x8*)(sm + swz(off));
            }
            #pragma unroll
            for (int mf = 0; mf < 2; ++mf)
                #pragma unroll
                for (int nf = 0; nf < 4; ++nf)
                    acc[mf][nf] = __builtin_amdgcn_mfma_f32_16x16x32_bf16(
                        cA[mf][kf], Bf[nf], acc[mf][nf], 0, 0, 0);
        }

        #pragma unroll
        for (int nf = 0; nf < 4; ++nf) {
            union { bf16_t hh[4]; uint2 u; } zp;
            #pragma unroll
            for (int r = 0; r < 4; ++r)
                zp.hh[r] = (bf16_t)(fsig(acc[0][nf][r]) * ftanh(acc[1][nf][r]));
            int off = 24576 + (nf * 16 + lr) * 128 + (w * 16 + g * 4) * 2;
            *(uint2*)(sm + swz(off)) = zp.u;
        }
        __syncthreads();

        f32x4 acc2[2][4];
        #pragma unroll
        for (int mf = 0; mf < 2; ++mf)
            #pragma unroll
            for (int nf = 0; nf < 4; ++nf) acc2[mf][nf] = bO[mf];
        #pragma unroll
        for (int kf = 0; kf < 2; ++kf) {
            bf16x8 Zf[4];
            #pragma unroll
            for (int nf = 0; nf < 4; ++nf) {
                int off = 24576 + (nf * 16 + lr) * 128 + (kf * 32 + g * 8) * 2;
                Zf[nf] = *(const bf16x8*)(sm + swz(off));
            }
            #pragma unroll
            for (int mf = 0; mf < 2; ++mf)
                #pragma unroll
                for (int nf = 0; nf < 4; ++nf)
                    acc2[mf][nf] = __builtin_amdgcn_mfma_f32_16x16x32_bf16(
                        oA[mf][kf], Zf[nf], acc2[mf][nf], 0, 0, 0);
        }

        #pragma unroll
        for (int nf = 0; nf < 4; ++nf) {
            int t = t0 + nf * 16 + lr;
            int c0 = w * 16 + g * 4;
            int xoff = 8192 + (nf * 16 + lr) * 128 + c0 * 2;
            bf16x4 xv = *(const bf16x4*)(sm + swz(xoff));
            bf16x4 ro, so;
            bf16_t* sp = skip + bb + (size_t)t * 64 + c0;
            if (first) {
                #pragma unroll
                for (int r = 0; r < 4; ++r) {
                    ro[r] = (bf16_t)(((float)xv[r] + acc2[0][nf][r]) * INV_SQRT2);
                    so[r] = (bf16_t)acc2[1][nf][r];
                }
            } else {
                bf16x4 sv = *(const bf16x4*)sp;
                #pragma unroll
                for (int r = 0; r < 4; ++r) {
                    ro[r] = (bf16_t)(((float)xv[r] + acc2[0][nf][r]) * INV_SQRT2);
                    so[r] = (bf16_t)((float)sv[r] + acc2[1][nf][r]);
                }
            }
            *(bf16x4*)(x_out + bb + (size_t)t * 64 + c0) = ro;
            *(bf16x4*)sp = so;
        }
        if (st == 0) __syncthreads();
    }
}

// ---------------------------------------------------------------------------
// Fused PAIR of layers (small dilations). Block = 64-t output tile.
// FROMAUD=1 (layer 0 only): X slab computed in-LDS from audio (in_conv
// fused); else staged from x_in via global_load_lds.
// ---------------------------------------------------------------------------
template<int D1, int D2, int YOFF, int NYR, int XOFF, int NXR, int FROMAUD>
__global__ __launch_bounds__(256) void fused_pair(
    const bf16_t* __restrict__ x_in, bf16_t* __restrict__ x_out,
    bf16_t* __restrict__ skip,
    const bf16_t* __restrict__ convpk, const bf16_t* __restrict__ oppk,
    const float* __restrict__ bias2, const float* __restrict__ op_b,
    const bf16_t* __restrict__ zpage,
    const float* __restrict__ audio,
    const float* __restrict__ in_W, const float* __restrict__ in_b,
    int layerA, int first)
{
    extern __shared__ char sm[];
    constexpr int NYF = NYR / 16;            // y n-frags
    constexpr int CF  = YOFF / 16;           // first central n-frag
    constexpr int YS  = NXR * 128;           // y slab byte base
    constexpr int ZS  = YS + NYR * 128;      // z slab byte base

    int tid = threadIdx.x;
    int w = __builtin_amdgcn_readfirstlane(tid >> 6);
    int l = tid & 63, lr = l & 15, g = l >> 4;
    int bid = blockIdx.x;                    // 256 tiles
    int tile = ((bid & 7) << 5) + (bid >> 3);
    int b = blockIdx.y;
    int t0 = tile * 64;
    size_t bb = (size_t)b * T * 64;
    const bf16_t* xb = x_in + bb;
    int c0 = w * 16 + g * 4;

    // ---- stage x slab ----------------------------------------------------
    if constexpr (FROMAUD) {
        #pragma unroll
        for (int r = 0; r < NXR / 32; ++r) {
            int q = r * 256 + tid;
            int row = q >> 3, c16 = q & 7;
            int ts = t0 - XOFF + row;
            bf16x8 o;
            if ((unsigned)ts < (unsigned)T) {
                float av = audio[(size_t)b * T + ts];
                #pragma unroll
                for (int j = 0; j < 8; ++j) {
                    int c = c16 * 8 + j;
                    o[j] = (bf16_t)fmaxf(fmaf(in_W[c], av, in_b[c]), 0.f);
                }
            } else {
                #pragma unroll
                for (int j = 0; j < 8; ++j) o[j] = (bf16_t)0.f;
            }
            *(bf16x8*)(sm + swz(row * 128 + c16 * 16)) = o;
        }
    } else {
        #pragma unroll
        for (int r = 0; r < NXR / 32; ++r) {
            int row = r * 32 + (tid >> 3), c16 = tid & 7;
            int ts = t0 - XOFF + row;
            int c16s = c16 ^ (row & 7);
            const bf16_t* src = ((unsigned)ts < (unsigned)T)
                ? (xb + (size_t)ts * 64 + c16s * 8)
                : (zpage + c16s * 8);
            __builtin_amdgcn_global_load_lds((glb_u32*)src,
                (lds_u32*)(sm + r * 4096 + w * 1024), 16, 0, 0);
        }
    }

    float skr[16];
    #pragma unroll
    for (int i = 0; i < 16; ++i) skr[i] = 0.f;

    // ---- layer A weights + biases ----------------------------------------
    bf16x8 cA[2][6];
    {
        const bf16_t* cw = convpk + (size_t)layerA * 128 * 192;
        #pragma unroll
        for (int mf = 0; mf < 2; ++mf)
            #pragma unroll
            for (int kf = 0; kf < 6; ++kf)
                cA[mf][kf] = *(const bf16x8*)(cw + (mf * 64 + w * 16 + lr) * 192 + kf * 32 + g * 8);
    }
    bf16x8 oA[2][2];
    {
        const bf16_t* ow = oppk + (size_t)layerA * 128 * 64;
        #pragma unroll
        for (int mf = 0; mf < 2; ++mf)
            #pragma unroll
            for (int kf = 0; kf < 2; ++kf)
                oA[mf][kf] = *(const bf16x8*)(ow + (mf * 64 + w * 16 + lr) * 64 + kf * 32 + g * 8);
    }
    f32x4 bC[2], bO[2];
    {
        const float* b2 = bias2 + (layerA * B + b) * 128;
        const float* ob = op_b + layerA * 2 * C;
        #pragma unroll
        for (int mf = 0; mf < 2; ++mf)
            #pragma unroll
            for (int r = 0; r < 4; ++r) {
                bC[mf][r] = b2[mf * 64 + c0 + r];
                bO[mf][r] = ob[mf * 64 + c0 + r];
            }
    }
    __syncthreads();                                    // x slab staged

    // ---- layer A conv (NYF n-frags) --------------------------------------
    f32x4 acc[2][NYF];
    #pragma unroll
    for (int mf = 0; mf < 2; ++mf)
        #pragma unroll
        for (int nf = 0; nf < NYF; ++nf) acc[mf][nf] = bC[mf];
    #pragma unroll
    for (int kf = 0; kf < 6; ++kf) {
        int tap = kf >> 1;
        int kc = (kf & 1) * 32;
        bf16x8 Bf[NYF];
        #pragma unroll
        for (int nf = 0; nf < NYF; ++nf) {
            int ix = (nf * 16 + lr) + (XOFF - YOFF) + (tap - 1) * D1;
            Bf[nf] = *(const bf16x8*)(sm + swz(ix * 128 + (kc + g * 8) * 2));
        }
        #pragma unroll
        for (int mf = 0; mf < 2; ++mf)
            #pragma unroll
            for (int nf = 0; nf < NYF; ++nf)
                acc[mf][nf] = __builtin_amdgcn_mfma_f32_16x16x32_bf16(
                    cA[mf][kf], Bf[nf], acc[mf][nf], 0, 0, 0);
    }

    // ---- gate A -> Z -----------------------------------------------------
    #pragma unroll
    for (int nf = 0; nf < NYF; ++nf) {
        union { bf16_t hh[4]; uint2 u; } zp;
        #pragma unroll
        for (int r = 0; r < 4; ++r)
            zp.hh[r] = (bf16_t)(fsig(acc[0][nf][r]) * ftanh(acc[1][nf][r]));
        int off = ZS + (nf * 16 + lr) * 128 + c0 * 2;
        *(uint2*)(sm + swz(off)) = zp.u;
    }
    __syncthreads();                                    // zA ready

    // ---- op A + epilogue A (y -> LDS, skip -> regs) ----------------------
    {
        f32x4 acc2[2][NYF];
        #pragma unroll
        for (int mf = 0; mf < 2; ++mf)
            #pragma unroll
            for (int nf = 0; nf < NYF; ++nf) acc2[mf][nf] = bO[mf];
        #pragma unroll
        for (int kf = 0; kf < 2; ++kf) {
            bf16x8 Zf[NYF];
            #pragma unroll
            for (int nf = 0; nf < NYF; ++nf) {
                int off = ZS + (nf * 16 + lr) * 128 + (kf * 32 + g * 8) * 2;
                Zf[nf] = *(const bf16x8*)(sm + swz(off));
            }
            #pragma unroll
            for (int mf = 0; mf < 2; ++mf)
                #pragma unroll
                for (int nf = 0; nf < NYF; ++nf)
                    acc2[mf][nf] = __builtin_amdgcn_mfma_f32_16x16x32_bf16(
                        oA[mf][kf], Zf[nf], acc2[mf][nf], 0, 0, 0);
        }
        #pragma unroll
        for (int nf = 0; nf < NYF; ++nf) {
            int iy = nf * 16 + lr;
            int ta = t0 - YOFF + iy;
            bool inr = ((unsigned)ta < (unsigned)T);
            int ixc = iy + (XOFF - YOFF);
            bf16x4 xv = *(const bf16x4*)(sm + swz(ixc * 128 + c0 * 2));
            bf16x4 yo;
            #pragma unroll
            for (int r = 0; r < 4; ++r) {
                float yv = ((float)xv[r] + acc2[0][nf][r]) * INV_SQRT2;
                yo[r] = inr ? (bf16_t)yv : (bf16_t)0.f;
                if (nf >= CF && nf < CF + 4)
                    skr[(nf - CF) * 4 + r] += acc2[1][nf][r];
            }
            *(bf16x4*)(sm + swz(YS + iy * 128 + c0 * 2)) = yo;
        }
    }

    // ---- layer B weights + biases ----------------------------------------
    int layerB = layerA + 1;
    bf16x8 cB[2][6];
    {
        const bf16_t* cw = convpk + (size_t)layerB * 128 * 192;
        #pragma unroll
        for (int mf = 0; mf < 2; ++mf)
            #pragma unroll
            for (int kf = 0; kf < 6; ++kf)
                cB[mf][kf] = *(const bf16x8*)(cw + (mf * 64 + w * 16 + lr) * 192 + kf * 32 + g * 8);
    }
    bf16x8 oB[2][2];
    {
        const bf16_t* ow = oppk + (size_t)layerB * 128 * 64;
        #pragma unroll
        for (int mf = 0; mf < 2; ++mf)
            #pragma unroll
            for (int kf = 0; kf < 2; ++kf)
                oB[mf][kf] = *(const bf16x8*)(ow + (mf * 64 + w * 16 + lr) * 64 + kf * 32 + g * 8);
    }
    f32x4 bCB[2], bOB[2];
    {
        const float* b2 = bias2 + (layerB * B + b) * 128;
        const float* ob = op_b + layerB * 2 * C;
        #pragma unroll
        for (int mf = 0; mf < 2; ++mf)
            #pragma unroll
            for (int r = 0; r < 4; ++r) {
                bCB[mf][r] = b2[mf * 64 + c0 + r];
                bOB[mf][r] = ob[mf * 64 + c0 + r];
            }
    }
    __syncthreads();                                    // y ready

    // ---- layer B conv (4 n-frags, central 64) ----------------------------
    f32x4 accB[2][4];
    #pragma unroll
    for (int mf = 0; mf < 2; ++mf)
        #pragma unroll
        for (int nf = 0; nf < 4; ++nf) accB[mf][nf] = bCB[mf];
    #pragma unroll
    for (int kf = 0; kf < 6; ++kf) {
        int tap = kf >> 1;
        int kc = (kf & 1) * 32;
        bf16x8 Bf[4];
        #pragma unroll
        for (int nf = 0; nf < 4; ++nf) {
            int jy = (nf * 16 + lr) + YOFF + (tap - 1) * D2;
            Bf[nf] = *(const bf16x8*)(sm + swz(YS + jy * 128 + (kc + g * 8) * 2));
        }
        #pragma unroll
        for (int mf = 0; mf < 2; ++mf)
            #pragma unroll
            for (int nf = 0; nf < 4; ++nf)
                accB[mf][nf] = __builtin_amdgcn_mfma_f32_16x16x32_bf16(
                    cB[mf][kf], Bf[nf], accB[mf][nf], 0, 0, 0);
    }

    // ---- gate B -> Z -----------------------------------------------------
    #pragma unroll
    for (int nf = 0; nf < 4; ++nf) {
        union { bf16_t hh[4]; uint2 u; } zp;
        #pragma unroll
        for (int r = 0; r < 4; ++r)
            zp.hh[r] = (bf16_t)(fsig(accB[0][nf][r]) * ftanh(accB[1][nf][r]));
        int off = ZS + (nf * 16 + lr) * 128 + c0 * 2;
        *(uint2*)(sm + swz(off)) = zp.u;
    }
    __syncthreads();                                    // zB ready

    // ---- op B + epilogue B (x_out global, ONE skip RMW) ------------------
    f32x4 acc2B[2][4];
    #pragma unroll
    for (int mf = 0; mf < 2; ++mf)
        #pragma unroll
        for (int nf = 0; nf < 4; ++nf) acc2B[mf][nf] = bOB[mf];
    #pragma unroll
    for (int kf = 0; kf < 2; ++kf) {
        bf16x8 Zf[4];
        #pragma unroll
        for (int nf = 0; nf < 4; ++nf) {
            int off = ZS + (nf * 16 + lr) * 128 + (kf * 32 + g * 8) * 2;
            Zf[nf] = *(const bf16x8*)(sm + swz(off));
        }
        #pragma unroll
        for (int mf = 0; mf < 2; ++mf)
            #pragma unroll
            for (int nf = 0; nf < 4; ++nf)
                acc2B[mf][nf] = __builtin_amdgcn_mfma_f32_16x16x32_bf16(
                    oB[mf][kf], Zf[nf], acc2B[mf][nf], 0, 0, 0);
    }
    #pragma unroll
    for (int nf = 0; nf < 4; ++nf) {
        int it = nf * 16 + lr;
        int t = t0 + it;
        int jyc = it + YOFF;
        bf16x4 yv = *(const bf16x4*)(sm + swz(YS + jyc * 128 + c0 * 2));
        bf16x4 ro, so;
        bf16_t* sp = skip + bb + (size_t)t * 64 + c0;
        if (first) {
            #pragma unroll
            for (int r = 0; r < 4; ++r) {
                ro[r] = (bf16_t)(((float)yv[r] + acc2B[0][nf][r]) * INV_SQRT2);
                so[r] = (bf16_t)(skr[nf * 4 + r] + acc2B[1][nf][r]);
            }
        } else {
            bf16x4 sv = *(const bf16x4*)sp;
            #pragma unroll
            for (int r = 0; r < 4; ++r) {
                ro[r] = (bf16_t)(((float)yv[r] + acc2B[0][nf][r]) * INV_SQRT2);
                so[r] = (bf16_t)((float)sv[r] + skr[nf * 4 + r] + acc2B[1][nf][r]);
            }
        }
        *(bf16x4*)(x_out + bb + (size_t)t * 64 + c0) = ro;
        *(bf16x4*)sp = so;
    }
}

// ---------------------------------------------------------------------------
__global__ __launch_bounds__(256) void final_kernel(
    const bf16_t* __restrict__ skip, const bf16_t* __restrict__ skpk,
    const float* __restrict__ sk_b,
    const float* __restrict__ out_W, const float* __restrict__ out_b,
    float* __restrict__ out)
{
    __shared__ uint4 tile_u[512];
    __shared__ float part[16][66];
    unsigned char* sm = (unsigned char*)tile_u;
    int tid = threadIdx.x;
    int w = __builtin_amdgcn_readfirstlane(tid >> 6);
    int l = tid & 63, lr = l & 15, g = l >> 4;
    int bid = blockIdx.x;
    int tile = ((bid & 7) << 5) + (bid >> 3);
    int b = blockIdx.y, t0 = tile * 64;
    const bf16_t* sb = skip + (size_t)b * T * 64;

    #pragma unroll
    for (int it = 0; it < 2; ++it) {
        int q = it * 256 + tid;
        int row = q >> 3, c16 = q & 7;
        uint4 val = *(const uint4*)(sb + (size_t)(t0 + row) * 64 + c16 * 8);
        *(uint4*)(sm + swz(row * 128 + c16 * 16)) = val;
    }

    bf16x8 aS[2];
    #pragma unroll
    for (int kf = 0; kf < 2; ++kf)
        aS[kf] = *(const bf16x8*)(skpk + (w * 16 + lr) * 64 + kf * 32 + g * 8);
    f32x4 acc[4];
    #pragma unroll
    for (int nf = 0; nf < 4; ++nf)
        #pragma unroll
        for (int r = 0; r < 4; ++r) acc[nf][r] = sk_b[w * 16 + g * 4 + r];
    __syncthreads();

    #pragma unroll
    for (int kf = 0; kf < 2; ++kf) {
        bf16x8 Bf[4];
        #pragma unroll
        for (int nf = 0; nf < 4; ++nf) {
            int off = (nf * 16 + lr) * 128 + (kf * 32 + g * 8) * 2;
            Bf[nf] = *(const bf16x8*)(sm + swz(off));
        }
        #pragma unroll
        for (int nf = 0; nf < 4; ++nf)
            acc[nf] = __builtin_amdgcn_mfma_f32_16x16x32_bf16(aS[kf], Bf[nf], acc[nf], 0, 0, 0);
    }

    #pragma unroll
    for (int nf = 0; nf < 4; ++nf) {
        float o = 0.f;
        #pragma unroll
        for (int r = 0; r < 4; ++r)
            o = fmaf(out_W[w * 16 + g * 4 + r], fmaxf(acc[nf][r], 0.f), o);
        part[w * 4 + g][nf * 16 + lr] = o;
    }
    __syncthreads();
    if (tid < 64) {
        float o = out_b[0];
        #pragma unroll
        for (int j = 0; j < 16; ++j) o += part[j][tid];
        out[(size_t)b * T + t0 + tid] = o;
    }
}

// ---------------------------------------------------------------------------
extern "C" void kernel_launch(void* const* d_in, const int* in_sizes, int n_in,
                              void* d_out, int out_size, void* d_ws, size_t ws_size,
                              hipStream_t stream) {
    const float* audio = (const float*)d_in[0];
    const int*   dstep = (const int*)d_in[1];
    const float* in_W  = (const float*)d_in[2];
    const float* in_b  = (const float*)d_in[3];
    const float* p1_W  = (const float*)d_in[4];
    const float* p1_b  = (const float*)d_in[5];
    const float* p2_W  = (const float*)d_in[6];
    const float* p2_b  = (const float*)d_in[7];
    const float* dw_W  = (const float*)d_in[8];
    const float* dw_b  = (const float*)d_in[9];
    const float* dp_W  = (const float*)d_in[10];
    const float* dp_b  = (const float*)d_in[11];
    const float* op_W  = (const float*)d_in[12];
    const float* op_b  = (const float*)d_in[13];
    const float* sk_W  = (const float*)d_in[14];
    const float* sk_b  = (const float*)d_in[15];
    const float* out_W = (const float*)d_in[16];
    const float* out_b = (const float*)d_in[17];

    float* ws = (float*)d_ws;
    const size_t NXE = (size_t)B * T * 64;
    float* h1    = ws;
    float* h2    = h1 + B * 512;
    float* bias2 = h2 + B * 512;                        // NL*B*128
    float* zpg   = bias2 + NL * B * 128;                // 512B zero page
    bf16_t* xA   = (bf16_t*)(zpg + 128);
    bf16_t* xB   = xA + NXE;
    bf16_t* skip = xB + NXE;
    bf16_t* convpk = skip + NXE;
    bf16_t* oppk   = convpk + (size_t)NL * 128 * 192;
    bf16_t* skpk   = oppk + (size_t)NL * 128 * 64;

    hipMemsetAsync(zpg, 0, 512, stream);
    hipLaunchKernelGGL(pack_weights, dim3(3856), dim3(256), 0, stream,
                       dw_W, op_W, sk_W, convpk, oppk, skpk);
    hipLaunchKernelGGL(cond_embp1, dim3(B, 8), dim3(256), 0, stream,
                       dstep, p1_W, p1_b, h1);
    hipLaunchKernelGGL(cond_p2, dim3(B, 8), dim3(256), 0, stream,
                       h1, p2_W, p2_b, h2);
    hipLaunchKernelGGL(cond_stage2b, dim3(NL, B), dim3(256), 0, stream,
                       h2, dp_W, dp_b, convpk, dw_b, bias2);

    bf16_t* bufs[2] = { xA, xB };
    int cur = 0;
    const bf16_t* zpgc = (const bf16_t*)zpg;
    for (int dec = 0; dec < 3; ++dec) {
        int base = dec * 10;
        if (dec == 0) {
            hipLaunchKernelGGL((fused_pair<1, 2, 16, 96, 32, 128, 1>),
                               dim3(T / 64, B), dim3(256), 40960, stream,
                               bufs[cur], bufs[cur ^ 1], skip, convpk, oppk,
                               bias2, op_b, zpgc, audio, in_W, in_b, 0, 1);
        } else {
            hipLaunchKernelGGL((fused_pair<1, 2, 16, 96, 32, 128, 0>),
                               dim3(T / 64, B), dim3(256), 40960, stream,
                               bufs[cur], bufs[cur ^ 1], skip, convpk, oppk,
                               bias2, op_b, zpgc, audio, in_W, in_b, base + 0, 0);
        }
        cur ^= 1;
        hipLaunchKernelGGL((fused_pair<4, 8, 16, 96, 32, 128, 0>),
                           dim3(T / 64, B), dim3(256), 40960, stream,
                           bufs[cur], bufs[cur ^ 1], skip, convpk, oppk,
                           bias2, op_b, zpgc, audio, in_W, in_b, base + 2, 0);
        cur ^= 1;
        hipLaunchKernelGGL((fused_pair<16, 32, 32, 128, 48, 160, 0>),
                           dim3(T / 64, B), dim3(256), 53248, stream,
                           bufs[cur], bufs[cur ^ 1], skip, convpk, oppk,
                           bias2, op_b, zpgc, audio, in_W, in_b, base + 4, 0);
        cur ^= 1;
        for (int j = 6; j < 10; ++j) {
            int dil = 1 << j;                            // 64,128,256,512
            hipLaunchKernelGGL(layer_kernel, dim3(T / 128, B), dim3(256), 0, stream,
                               bufs[cur], bufs[cur ^ 1], skip, convpk, oppk,
                               bias2, op_b, zpgc, base + j, dil, 0);
            cur ^= 1;
        }
    }
    hipLaunchKernelGGL(final_kernel, dim3(T / 64, B), dim3(256), 0, stream,
                       skip, skpk, sk_b, out_W, out_b, (float*)d_out);
}